// Round 1
// baseline (231.778 us; speedup 1.0000x reference)
//
#include <hip/hip_runtime.h>
#include <math.h>

#define KK 40
#define HH 16
#define DD 128
#define NN 512
#define X0C 0.085f
#define LOG2E 1.4426950408889634f
#define LN2f 0.6931471805599453f
#define SCB 17.0f   // per-step 2^-17 scaling folded into P~

// ws layout (float offsets). Total ~1.12M floats (~4.5 MB).
enum {
  OFF_W    = 0,                  // 512*128
  OFF_AW   = OFF_W + NN*DD,      // 512*16
  OFF_BW   = OFF_AW + NN*HH,     // 512*16
  OFF_WPB  = OFF_BW + NN*HH,     // 512*40
  OFF_WBG  = OFF_WPB + NN*KK,    // 512*40
  OFF_SA   = OFF_WBG + NN*KK,    // 40*40
  OFF_TA   = OFF_SA + KK*KK,
  OFF_TB   = OFF_TA + KK*KK,
  OFF_H    = OFF_TB + KK*KK,     // 514*16
  OFF_HP   = OFF_H + 514*HH,     // 514*16
  OFF_PREA = OFF_HP + 514*HH,    // 513*40
  OFF_E    = OFF_PREA + 513*KK,  // 512*40
  OFF_A0   = OFF_E + NN*KK,      // 40*40 x4
  OFF_A1   = OFF_A0 + KK*KK,
  OFF_A2   = OFF_A1 + KK*KK,
  OFF_A3   = OFF_A2 + KK*KK,
  OFF_LA0  = OFF_A3 + KK*KK,     // 40
  OFF_FIN  = OFF_LA0 + KK,       // 40
  OFF_PT   = OFF_FIN + KK,       // 511*1600
  OFF_CM   = OFF_PT + 511*KK*KK, // 64*1600
  OFF_LS   = OFF_CM + 64*KK*KK,  // 64
  WS_FLOATS = OFF_LS + 64
};

__device__ __forceinline__ float sigm(float x) {
  return 1.f / (1.f + __expf(-x));
}

// K1: gather W=E[words], aw=Mw@W, bw=MPw@W, wpartB=UwB@W, WBg=rowsum(WlinB[words]),
//     plus SA/TA/TB small matmuls (blocks 512..514).
__global__ __launch_bounds__(256) void k1_prep(
    const float* __restrict__ E, const float* __restrict__ M, const float* __restrict__ MP,
    const float* __restrict__ T, const float* __restrict__ UA, const float* __restrict__ UB,
    const float* __restrict__ WlinB, const int* __restrict__ words, float* __restrict__ ws)
{
  int b = blockIdx.x, t = threadIdx.x;
  if (b < NN) {
    __shared__ float wrow[DD];
    __shared__ float brow[KK*KK];
    int w = words[b];
    if (t < DD) { float v = E[w*DD + t]; wrow[t] = v; ws[OFF_W + b*DD + t] = v; }
    for (int idx = t; idx < KK*KK; idx += 256) brow[idx] = WlinB[(size_t)w*(KK*KK) + idx];
    __syncthreads();
    if (t < 16) {                       // aw: M[:,17:145] @ w
      float acc = 0.f; const float* mr = M + t*145 + 17;
      for (int d = 0; d < DD; ++d) acc += mr[d]*wrow[d];
      ws[OFF_AW + b*HH + t] = acc;
    } else if (t < 32) {                // bw: MP[:,1:129] @ w
      int j = t - 16; float acc = 0.f; const float* mr = MP + j*145 + 1;
      for (int d = 0; d < DD; ++d) acc += mr[d]*wrow[d];
      ws[OFF_BW + b*HH + j] = acc;
    } else if (t < 72) {                // wpartB: UB[:,145:273] @ w
      int o = t - 32; float acc = 0.f; const float* ur = UB + o*289 + 145;
      for (int d = 0; d < DD; ++d) acc += ur[d]*wrow[d];
      ws[OFF_WPB + b*KK + o] = acc;
    }
    if (t < KK) {                       // WBg[b,u] = sum_s WlinB[w, s*40+u]
      float acc = 0.f;
      for (int s = 0; s < KK; ++s) acc += brow[s*KK + t];
      ws[OFF_WBG + b*KK + t] = acc;
    }
  } else {
    int which = b - NN;                 // 0:SA 1:TA 2:TB
    __shared__ float Tl[KK*DD];
    for (int idx = t; idx < KK*DD; idx += 256) Tl[idx] = T[idx];
    __syncthreads();
    const float* U = (which == 2) ? UB : UA;
    int off = (which == 1) ? 145 : 17;
    int dsto = (which == 0) ? OFF_SA : (which == 1) ? OFF_TA : OFF_TB;
    for (int out = t; out < KK*KK; out += 256) {
      int r = out / KK, s = out % KK;
      const float* ur = U + r*289 + off;
      float acc = 0.f;
      for (int d = 0; d < DD; ++d) acc += ur[d]*Tl[s*DD + d];
      ws[dsto + out] = acc;
    }
  }
}

// K2: the two sequential RNN scans. block 0 = forward, block 1 = backward. 1 wave each.
__global__ __launch_bounds__(64) void k2_rnn(const float* __restrict__ M,
                                             const float* __restrict__ MP,
                                             float* __restrict__ ws)
{
  int lane = threadIdx.x;
  int row = lane & 15;
  bool fwd = (blockIdx.x == 0);
  const float* Mat = fwd ? M : MP;
  const float* drv = ws + (fwd ? OFF_AW : OFF_BW);
  float* out = ws + (fwd ? OFF_H : OFF_HP);
  __shared__ float hbuf[16];
  __shared__ float dbuf[NN*HH];   // 32 KB: stage drive terms
  for (int idx = lane; idx < NN*HH; idx += 64) dbuf[idx] = drv[idx];
  float base = Mat[row*145];
  int hoff = fwd ? 1 : 129;       // Mh cols 1..16 ; MPh cols 129..144
  float mh[HH];
  #pragma unroll
  for (int k2 = 0; k2 < HH; ++k2) mh[k2] = Mat[row*145 + hoff + k2];
  if (lane < 16) { hbuf[lane] = 0.f; out[lane] = 0.f; out[513*HH + lane] = 0.f; }
  __syncthreads();
  for (int step = 0; step < NN; ++step) {
    int i = fwd ? step : (NN - 1 - step);
    float acc = base + dbuf[i*HH + row];
    #pragma unroll
    for (int k2 = 0; k2 < HH; ++k2) acc += mh[k2] * hbuf[k2];
    float h2 = sigm(acc);
    __syncthreads();
    if (lane < 16) { hbuf[lane] = h2; out[(i + 1)*HH + lane] = h2; }
    __syncthreads();
  }
}

// K3: preA[i,r] (i=0..512), and preB -> e[i,t] (i=0..511) exactly.
__global__ __launch_bounds__(64) void k3_pre(const float* __restrict__ UA,
                                             const float* __restrict__ UB,
                                             float* __restrict__ ws)
{
  int i = blockIdx.x;   // 0..512
  int t = threadIdx.x;
  __shared__ float hl[16], hal[16], hbl[16];
  if (t < 16) {
    hl[t]  = ws[OFF_H + i*HH + t];
    hal[t] = (i >= 2) ? ws[OFF_HP + (i - 2)*HH + t] : 0.f;
    hbl[t] = (i >= 1) ? ws[OFF_HP + (i - 1)*HH + t] : 0.f;
  }
  __syncthreads();
  if (t < KK) {
    const float* ua = UA + t*289;
    float accA = ua[0];
    #pragma unroll
    for (int k2 = 0; k2 < HH; ++k2) accA += hl[k2]*ua[1 + k2] + hal[k2]*ua[273 + k2];
    ws[OFF_PREA + i*KK + t] = accA;
    if (i < NN) {
      const float* ub = UB + t*289;
      float accB = ub[0] + ((i >= 1) ? ws[OFF_WPB + (i - 1)*KK + t] : 0.f);
      #pragma unroll
      for (int k2 = 0; k2 < HH; ++k2) accB += hl[k2]*ub[1 + k2] + hbl[k2]*ub[273 + k2];
      float ev = 0.f;
      for (int u = 0; u < KK; ++u) {
        float y = accB + ws[OFF_TB + t*KK + u];
        ev += ws[OFF_WBG + i*KK + u] * sigm(y);
      }
      ws[OFF_E + i*KK + t] = ev;
    }
  }
}

// K4: Taylor coefficient tables Am[r,o] = sum_st (sigma^(m)(y)/m!) * WlinA[o,st],
//     y = X0 + SA[r,s] + TA[r,t]. 40 blocks (r) x 640 threads (o=t>>4, j=t&15).
__global__ __launch_bounds__(640) void k4_coef(const float* __restrict__ WlinA,
                                               float* __restrict__ ws)
{
  int r = blockIdx.x, t = threadIdx.x;
  __shared__ float SAl[KK], TAl[KK];
  if (t < KK) SAl[t] = ws[OFF_SA + r*KK + t];
  else if (t < 2*KK) TAl[t - KK] = ws[OFF_TA + r*KK + (t - KK)];
  __syncthreads();
  int o = t >> 4, j = t & 15;
  float a0 = 0, a1 = 0, a2 = 0, a3 = 0;
  for (int st = j; st < KK*KK; st += 16) {
    int s = st / KK, u = st - s*KK;
    float y = X0C + SAl[s] + TAl[u];
    float sg = sigm(y);
    float s1 = sg*(1.f - sg);
    float d2 = s1*(1.f - 2.f*sg)*0.5f;
    float d3 = s1*(1.f - 6.f*sg*(1.f - sg))*(1.f/6.f);
    float w = WlinA[o*1600 + st];
    a0 += sg*w; a1 += s1*w; a2 += d2*w; a3 += d3*w;
  }
  #pragma unroll
  for (int m = 1; m <= 8; m <<= 1) {
    a0 += __shfl_xor(a0, m); a1 += __shfl_xor(a1, m);
    a2 += __shfl_xor(a2, m); a3 += __shfl_xor(a3, m);
  }
  if (j == 0) {
    ws[OFF_A0 + r*KK + o] = a0; ws[OFF_A1 + r*KK + o] = a1;
    ws[OFF_A2 + r*KK + o] = a2; ws[OFF_A3 + r*KK + o] = a3;
  }
}

// K5: expand logphiA via cubic Horner; emit P~[i]=exp(lp+e-17ln2) for i=1..511,
//     la0 (i=0, r=BOS=0) and fin (i=512, o=EOS=1).
__global__ __launch_bounds__(256) void k5_expand(float* __restrict__ ws)
{
  int i = blockIdx.x;   // 0..512
  int t = threadIdx.x;
  __shared__ float pr[KK], er[KK];
  if (t < KK) {
    pr[t] = ws[OFF_PREA + i*KK + t];
    er[t] = (i < NN) ? ws[OFF_E + i*KK + t] : 0.f;
  }
  __syncthreads();
  for (int idx = t; idx < KK*KK; idx += 256) {
    int r = idx / KK, o = idx - r*KK;
    float d = pr[r] - X0C;
    float lp = ((ws[OFF_A3 + idx]*d + ws[OFF_A2 + idx])*d + ws[OFF_A1 + idx])*d + ws[OFF_A0 + idx];
    if (i == 0) {
      if (r == 0) ws[OFF_LA0 + o] = lp + er[o];
    } else if (i == NN) {
      if (o == 1) ws[OFF_FIN + r] = lp;
    } else {
      ws[OFF_PT + (size_t)(i - 1)*1600 + idx] = exp2f((lp + er[o])*LOG2E - SCB);
    }
  }
}

// K6: parallel chunk products of 8 consecutive P~ matrices (64 chunks), renormalized.
__global__ __launch_bounds__(256) void k6_chunk(float* __restrict__ ws)
{
  int c = blockIdx.x, t = threadIdx.x;
  int s0 = 1 + 8*c;
  int len = min(8, NN - s0);
  __shared__ float buf[2][KK*KK];
  __shared__ float Pb[KK*KK];
  __shared__ float red[4];
  int p = 0;
  for (int idx = t; idx < KK*KK; idx += 256) buf[0][idx] = ws[OFF_PT + (size_t)(s0 - 1)*1600 + idx];
  __syncthreads();
  for (int stp = 1; stp < len; ++stp) {
    for (int idx = t; idx < KK*KK; idx += 256) Pb[idx] = ws[OFF_PT + (size_t)(s0 + stp - 1)*1600 + idx];
    __syncthreads();
    for (int idx = t; idx < KK*KK; idx += 256) {
      int r = idx / KK, o = idx - r*KK;
      float acc = 0.f;
      for (int k2 = 0; k2 < KK; ++k2) acc += buf[p][r*KK + k2]*Pb[k2*KK + o];
      buf[p ^ 1][idx] = acc;
    }
    __syncthreads();
    p ^= 1;
  }
  float mx = 0.f;
  for (int idx = t; idx < KK*KK; idx += 256) mx = fmaxf(mx, buf[p][idx]);
  #pragma unroll
  for (int m = 1; m <= 32; m <<= 1) mx = fmaxf(mx, __shfl_xor(mx, m));
  if ((t & 63) == 0) red[t >> 6] = mx;
  __syncthreads();
  mx = fmaxf(fmaxf(red[0], red[1]), fmaxf(red[2], red[3]));
  float inv = 1.f / mx;
  for (int idx = t; idx < KK*KK; idx += 256) ws[OFF_CM + c*1600 + idx] = buf[p][idx]*inv;
  if (t == 0) ws[OFF_LS + c] = logf(mx) + (float)len*(SCB*LN2f);
}

// K7: final 64-step scan over chunk matrices + termination. 1 block, 1 wave.
__global__ __launch_bounds__(64) void k7_final(float* __restrict__ ws, float* __restrict__ out)
{
  int lane = threadIdx.x;
  __shared__ float av[KK];
  float v = (lane < KK) ? ws[OFF_LA0 + lane] : -1e30f;
  float m0 = v;
  #pragma unroll
  for (int m = 1; m <= 32; m <<= 1) m0 = fmaxf(m0, __shfl_xor(m0, m));
  if (lane < KK) av[lane] = __expf(v - m0);
  float lacc = m0;
  __syncthreads();
  for (int c = 0; c < 64; ++c) {
    float s = 0.f;
    if (lane < KK) {
      const float* mc = ws + OFF_CM + c*1600;
      for (int r = 0; r < KK; ++r) s += av[r]*mc[r*KK + lane];
    }
    float mx = s;
    #pragma unroll
    for (int m = 1; m <= 32; m <<= 1) mx = fmaxf(mx, __shfl_xor(mx, m));
    __syncthreads();
    if (lane < KK) av[lane] = s / mx;
    lacc += logf(mx) + ws[OFF_LS + c];
    __syncthreads();
  }
  float tv = (lane < KK) ? av[lane]*__expf(ws[OFF_FIN + lane]) : 0.f;
  #pragma unroll
  for (int m = 1; m <= 32; m <<= 1) tv += __shfl_xor(tv, m);
  if (lane == 0) out[0] = lacc + logf(tv);
}

extern "C" void kernel_launch(void* const* d_in, const int* in_sizes, int n_in,
                              void* d_out, int out_size, void* d_ws, size_t ws_size,
                              hipStream_t stream) {
  const float* E     = (const float*)d_in[0];
  const float* M     = (const float*)d_in[1];
  const float* MP    = (const float*)d_in[2];
  const float* T     = (const float*)d_in[3];
  const float* UA    = (const float*)d_in[4];
  const float* UB    = (const float*)d_in[5];
  const float* WlinA = (const float*)d_in[6];
  const float* WlinB = (const float*)d_in[7];
  const int*   words = (const int*)d_in[8];
  float* ws  = (float*)d_ws;       // needs WS_FLOATS*4 ~ 4.5 MB
  float* out = (float*)d_out;

  k1_prep<<<dim3(NN + 3), dim3(256), 0, stream>>>(E, M, MP, T, UA, UB, WlinB, words, ws);
  k2_rnn<<<dim3(2), dim3(64), 0, stream>>>(M, MP, ws);
  k3_pre<<<dim3(NN + 1), dim3(64), 0, stream>>>(UA, UB, ws);
  k4_coef<<<dim3(KK), dim3(640), 0, stream>>>(WlinA, ws);
  k5_expand<<<dim3(NN + 1), dim3(256), 0, stream>>>(ws);
  k6_chunk<<<dim3(64), dim3(256), 0, stream>>>(ws);
  k7_final<<<dim3(1), dim3(64), 0, stream>>>(ws, out);
}

// Round 2
// 165.705 us; speedup vs baseline: 1.3987x; 1.3987x over previous
//
#include <hip/hip_runtime.h>
#include <math.h>

#define KK 40
#define HH 16
#define DD 128
#define NN 512
#define X0C 0.085f
#define LOG2E 1.4426950408889634f
#define LN2f 0.6931471805599453f
#define SCB 17.0f   // per-step 2^-17 scaling folded into P~

// ws layout (float offsets). Total ~1.13M floats (~4.6 MB).
enum {
  OFF_W    = 0,                  // 512*128
  OFF_AW   = OFF_W + NN*DD,      // 512*16
  OFF_BW   = OFF_AW + NN*HH,     // 512*16
  OFF_WPB  = OFF_BW + NN*HH,     // 512*40
  OFF_WBG  = OFF_WPB + NN*KK,    // 512*40
  OFF_SA   = OFF_WBG + NN*KK,    // 40*40
  OFF_TA   = OFF_SA + KK*KK,
  OFF_TB   = OFF_TA + KK*KK,
  OFF_H    = OFF_TB + KK*KK,     // 514*16
  OFF_HP   = OFF_H + 514*HH,     // 514*16
  OFF_PREA = OFF_HP + 514*HH,    // 513*40
  OFF_E    = OFF_PREA + 513*KK,  // 512*40
  OFF_A0   = OFF_E + NN*KK,      // 40*40 x4
  OFF_A1   = OFF_A0 + KK*KK,
  OFF_A2   = OFF_A1 + KK*KK,
  OFF_A3   = OFF_A2 + KK*KK,
  OFF_LA0  = OFF_A3 + KK*KK,     // 40
  OFF_FIN  = OFF_LA0 + KK,       // 40
  OFF_PT   = OFF_FIN + KK,       // 511*1600
  OFF_CM   = OFF_PT + 511*KK*KK, // 64*1600
  OFF_LS   = OFF_CM + 64*KK*KK,  // 64
  OFF_CM2  = OFF_LS + 64,        // 8*1600
  OFF_LS2  = OFF_CM2 + 8*KK*KK,  // 8
  WS_FLOATS = OFF_LS2 + 8
};

__device__ __forceinline__ float sigm(float x) {
  return 1.f / (1.f + __expf(-x));
}

// K1: gather W=E[words], aw=Mw@W, bw=MPw@W, wpartB=UwB@W, WBg=rowsum(WlinB[words]),
//     plus SA/TA/TB small matmuls (blocks 512..514).
__global__ __launch_bounds__(256) void k1_prep(
    const float* __restrict__ E, const float* __restrict__ M, const float* __restrict__ MP,
    const float* __restrict__ T, const float* __restrict__ UA, const float* __restrict__ UB,
    const float* __restrict__ WlinB, const int* __restrict__ words, float* __restrict__ ws)
{
  int b = blockIdx.x, t = threadIdx.x;
  if (b < NN) {
    __shared__ float wrow[DD];
    __shared__ float brow[KK*KK];
    int w = words[b];
    if (t < DD) { float v = E[w*DD + t]; wrow[t] = v; ws[OFF_W + b*DD + t] = v; }
    for (int idx = t; idx < KK*KK; idx += 256) brow[idx] = WlinB[(size_t)w*(KK*KK) + idx];
    __syncthreads();
    if (t < 16) {                       // aw: M[:,17:145] @ w
      float acc = 0.f; const float* mr = M + t*145 + 17;
      for (int d = 0; d < DD; ++d) acc += mr[d]*wrow[d];
      ws[OFF_AW + b*HH + t] = acc;
    } else if (t < 32) {                // bw: MP[:,1:129] @ w
      int j = t - 16; float acc = 0.f; const float* mr = MP + j*145 + 1;
      for (int d = 0; d < DD; ++d) acc += mr[d]*wrow[d];
      ws[OFF_BW + b*HH + j] = acc;
    } else if (t < 72) {                // wpartB: UB[:,145:273] @ w
      int o = t - 32; float acc = 0.f; const float* ur = UB + o*289 + 145;
      for (int d = 0; d < DD; ++d) acc += ur[d]*wrow[d];
      ws[OFF_WPB + b*KK + o] = acc;
    }
    if (t < KK) {                       // WBg[b,u] = sum_s WlinB[w, s*40+u]
      float acc = 0.f;
      for (int s = 0; s < KK; ++s) acc += brow[s*KK + t];
      ws[OFF_WBG + b*KK + t] = acc;
    }
  } else {
    int which = b - NN;                 // 0:SA 1:TA 2:TB
    __shared__ float Tl[KK*DD];
    for (int idx = t; idx < KK*DD; idx += 256) Tl[idx] = T[idx];
    __syncthreads();
    const float* U = (which == 2) ? UB : UA;
    int off = (which == 1) ? 145 : 17;
    int dsto = (which == 0) ? OFF_SA : (which == 1) ? OFF_TA : OFF_TB;
    for (int out = t; out < KK*KK; out += 256) {
      int r = out / KK, s = out % KK;
      const float* ur = U + r*289 + off;
      float acc = 0.f;
      for (int d = 0; d < DD; ++d) acc += ur[d]*Tl[s*DD + d];
      ws[dsto + out] = acc;
    }
  }
}

// K2: chunk-parallel RNN scans. Contraction |dh'/dh| <= 0.25*16*0.01 = 0.04 per
// step => 8 warm-up steps from h=0 give state error <= 0.04^8 ~ 7e-12 (< fp32 ulp).
// 128 chunks (64 fwd + 64 bwd) of 8 real steps each; one 16-lane group per chunk;
// cross-lane h broadcast via width-16 shuffles (no LDS, no barriers).
__global__ __launch_bounds__(64) void k2_rnn(const float* __restrict__ M,
                                             const float* __restrict__ MP,
                                             float* __restrict__ ws)
{
  int lane = threadIdx.x;
  int row = lane & 15;
  int g = blockIdx.x*4 + (lane >> 4);   // 0..127
  int dirb = g >> 6;                    // 0 fwd, 1 bwd
  int c = g & 63;
  const float* Mat = dirb ? MP : M;
  const float* drv = ws + (dirb ? OFF_BW : OFF_AW);
  float* out = ws + (dirb ? OFF_HP : OFF_H);
  float base = Mat[row*145];
  int hoff = dirb ? 129 : 1;            // Mh cols 1..16 ; MPh cols 129..144
  float mh[HH];
  #pragma unroll
  for (int k = 0; k < HH; ++k) mh[k] = Mat[row*145 + hoff + k];
  float dr[16];
  #pragma unroll
  for (int j = 0; j < 16; ++j) {
    int i = dirb ? (8*c + 15 - j) : (8*c - 8 + j);
    int ic = min(max(i, 0), NN - 1);
    dr[j] = drv[ic*HH + row];
  }
  float h = 0.f;
  #pragma unroll
  for (int j = 0; j < 16; ++j) {
    int i = dirb ? (8*c + 15 - j) : (8*c - 8 + j);
    bool valid = (i >= 0) && (i < NN);
    float acc = base + dr[j];
    #pragma unroll
    for (int k = 0; k < HH; ++k) acc += mh[k] * __shfl(h, k, 16);
    float h2 = sigm(acc);
    if (valid) h = h2;                  // invalid steps keep h (=0 true init)
    if (valid && j >= 8) out[(i + 1)*HH + row] = h;
  }
  if (blockIdx.x == 0 && lane < 16) {   // boundary zeros
    ws[OFF_H + lane] = 0.f;  ws[OFF_H + 513*HH + lane] = 0.f;
    ws[OFF_HP + lane] = 0.f; ws[OFF_HP + 513*HH + lane] = 0.f;
  }
}

// K3: preA[i,r] (i=0..512), and preB -> e[i,t] (i=0..511) exactly.
__global__ __launch_bounds__(64) void k3_pre(const float* __restrict__ UA,
                                             const float* __restrict__ UB,
                                             float* __restrict__ ws)
{
  int i = blockIdx.x;   // 0..512
  int t = threadIdx.x;
  __shared__ float hl[16], hal[16], hbl[16];
  if (t < 16) {
    hl[t]  = ws[OFF_H + i*HH + t];
    hal[t] = (i >= 2) ? ws[OFF_HP + (i - 2)*HH + t] : 0.f;
    hbl[t] = (i >= 1) ? ws[OFF_HP + (i - 1)*HH + t] : 0.f;
  }
  __syncthreads();
  if (t < KK) {
    const float* ua = UA + t*289;
    float accA = ua[0];
    #pragma unroll
    for (int k2 = 0; k2 < HH; ++k2) accA += hl[k2]*ua[1 + k2] + hal[k2]*ua[273 + k2];
    ws[OFF_PREA + i*KK + t] = accA;
    if (i < NN) {
      const float* ub = UB + t*289;
      float accB = ub[0] + ((i >= 1) ? ws[OFF_WPB + (i - 1)*KK + t] : 0.f);
      #pragma unroll
      for (int k2 = 0; k2 < HH; ++k2) accB += hl[k2]*ub[1 + k2] + hbl[k2]*ub[273 + k2];
      float ev = 0.f;
      for (int u = 0; u < KK; ++u) {
        float y = accB + ws[OFF_TB + t*KK + u];
        ev += ws[OFF_WBG + i*KK + u] * sigm(y);
      }
      ws[OFF_E + i*KK + t] = ev;
    }
  }
}

// K4: Taylor coefficient tables Am[r,o] = sum_st (sigma^(m)(y)/m!) * WlinA[o,st],
//     y = X0 + SA[r,s] + TA[r,t]. 40 blocks (r) x 640 threads (o=t>>4, j=t&15).
__global__ __launch_bounds__(640) void k4_coef(const float* __restrict__ WlinA,
                                               float* __restrict__ ws)
{
  int r = blockIdx.x, t = threadIdx.x;
  __shared__ float SAl[KK], TAl[KK];
  if (t < KK) SAl[t] = ws[OFF_SA + r*KK + t];
  else if (t < 2*KK) TAl[t - KK] = ws[OFF_TA + r*KK + (t - KK)];
  __syncthreads();
  int o = t >> 4, j = t & 15;
  float a0 = 0, a1 = 0, a2 = 0, a3 = 0;
  for (int st = j; st < KK*KK; st += 16) {
    int s = st / KK, u = st - s*KK;
    float y = X0C + SAl[s] + TAl[u];
    float sg = sigm(y);
    float s1 = sg*(1.f - sg);
    float d2 = s1*(1.f - 2.f*sg)*0.5f;
    float d3 = s1*(1.f - 6.f*sg*(1.f - sg))*(1.f/6.f);
    float w = WlinA[o*1600 + st];
    a0 += sg*w; a1 += s1*w; a2 += d2*w; a3 += d3*w;
  }
  #pragma unroll
  for (int m = 1; m <= 8; m <<= 1) {
    a0 += __shfl_xor(a0, m); a1 += __shfl_xor(a1, m);
    a2 += __shfl_xor(a2, m); a3 += __shfl_xor(a3, m);
  }
  if (j == 0) {
    ws[OFF_A0 + r*KK + o] = a0; ws[OFF_A1 + r*KK + o] = a1;
    ws[OFF_A2 + r*KK + o] = a2; ws[OFF_A3 + r*KK + o] = a3;
  }
}

// K5: expand logphiA via cubic Horner; emit P~[i]=exp(lp+e-17ln2) for i=1..511,
//     la0 (i=0, r=BOS=0) and fin (i=512, o=EOS=1).
__global__ __launch_bounds__(256) void k5_expand(float* __restrict__ ws)
{
  int i = blockIdx.x;   // 0..512
  int t = threadIdx.x;
  __shared__ float pr[KK], er[KK];
  if (t < KK) {
    pr[t] = ws[OFF_PREA + i*KK + t];
    er[t] = (i < NN) ? ws[OFF_E + i*KK + t] : 0.f;
  }
  __syncthreads();
  for (int idx = t; idx < KK*KK; idx += 256) {
    int r = idx / KK, o = idx - r*KK;
    float d = pr[r] - X0C;
    float lp = ((ws[OFF_A3 + idx]*d + ws[OFF_A2 + idx])*d + ws[OFF_A1 + idx])*d + ws[OFF_A0 + idx];
    if (i == 0) {
      if (r == 0) ws[OFF_LA0 + o] = lp + er[o];
    } else if (i == NN) {
      if (o == 1) ws[OFF_FIN + r] = lp;
    } else {
      ws[OFF_PT + (size_t)(i - 1)*1600 + idx] = exp2f((lp + er[o])*LOG2E - SCB);
    }
  }
}

// K6: parallel chunk products of 8 consecutive P~ matrices (64 chunks), renormalized.
__global__ __launch_bounds__(256) void k6_chunk(float* __restrict__ ws)
{
  int c = blockIdx.x, t = threadIdx.x;
  int s0 = 1 + 8*c;
  int len = min(8, NN - s0);
  __shared__ float buf[2][KK*KK];
  __shared__ float Pb[KK*KK];
  __shared__ float red[4];
  int p = 0;
  for (int idx = t; idx < KK*KK; idx += 256) buf[0][idx] = ws[OFF_PT + (size_t)(s0 - 1)*1600 + idx];
  __syncthreads();
  for (int stp = 1; stp < len; ++stp) {
    for (int idx = t; idx < KK*KK; idx += 256) Pb[idx] = ws[OFF_PT + (size_t)(s0 + stp - 1)*1600 + idx];
    __syncthreads();
    for (int idx = t; idx < KK*KK; idx += 256) {
      int r = idx / KK, o = idx - r*KK;
      float acc = 0.f;
      for (int k2 = 0; k2 < KK; ++k2) acc += buf[p][r*KK + k2]*Pb[k2*KK + o];
      buf[p ^ 1][idx] = acc;
    }
    __syncthreads();
    p ^= 1;
  }
  float mx = 0.f;
  for (int idx = t; idx < KK*KK; idx += 256) mx = fmaxf(mx, buf[p][idx]);
  #pragma unroll
  for (int m = 1; m <= 32; m <<= 1) mx = fmaxf(mx, __shfl_xor(mx, m));
  if ((t & 63) == 0) red[t >> 6] = mx;
  __syncthreads();
  mx = fmaxf(fmaxf(red[0], red[1]), fmaxf(red[2], red[3]));
  float inv = 1.f / mx;
  for (int idx = t; idx < KK*KK; idx += 256) ws[OFF_CM + c*1600 + idx] = buf[p][idx]*inv;
  if (t == 0) ws[OFF_LS + c] = __logf(mx) + (float)len*(SCB*LN2f);
}

// K6b: second level — product of 8 consecutive CM matrices (8 super-chunks).
__global__ __launch_bounds__(256) void k6b_chunk2(float* __restrict__ ws)
{
  int c = blockIdx.x, t = threadIdx.x;   // c = 0..7
  __shared__ float buf[2][KK*KK];
  __shared__ float Pb[KK*KK];
  __shared__ float red[4];
  int p = 0;
  for (int idx = t; idx < KK*KK; idx += 256) buf[0][idx] = ws[OFF_CM + (8*c)*1600 + idx];
  __syncthreads();
  for (int stp = 1; stp < 8; ++stp) {
    for (int idx = t; idx < KK*KK; idx += 256) Pb[idx] = ws[OFF_CM + (8*c + stp)*1600 + idx];
    __syncthreads();
    for (int idx = t; idx < KK*KK; idx += 256) {
      int r = idx / KK, o = idx - r*KK;
      float acc = 0.f;
      for (int k2 = 0; k2 < KK; ++k2) acc += buf[p][r*KK + k2]*Pb[k2*KK + o];
      buf[p ^ 1][idx] = acc;
    }
    __syncthreads();
    p ^= 1;
  }
  float mx = 0.f;
  for (int idx = t; idx < KK*KK; idx += 256) mx = fmaxf(mx, buf[p][idx]);
  #pragma unroll
  for (int m = 1; m <= 32; m <<= 1) mx = fmaxf(mx, __shfl_xor(mx, m));
  if ((t & 63) == 0) red[t >> 6] = mx;
  __syncthreads();
  mx = fmaxf(fmaxf(red[0], red[1]), fmaxf(red[2], red[3]));
  float inv = 1.f / mx;
  for (int idx = t; idx < KK*KK; idx += 256) ws[OFF_CM2 + c*1600 + idx] = buf[p][idx]*inv;
  if (t == 0) {
    float ls = __logf(mx);
    for (int j = 0; j < 8; ++j) ls += ws[OFF_LS + 8*c + j];
    ws[OFF_LS2 + c] = ls;
  }
}

// K7: final 8-step scan over super-chunk matrices + termination. 1 block, 1 wave.
__global__ __launch_bounds__(64) void k7_final(float* __restrict__ ws, float* __restrict__ out)
{
  int lane = threadIdx.x;
  __shared__ float av[KK];
  float v = (lane < KK) ? ws[OFF_LA0 + lane] : -1e30f;
  float m0 = v;
  #pragma unroll
  for (int m = 1; m <= 32; m <<= 1) m0 = fmaxf(m0, __shfl_xor(m0, m));
  if (lane < KK) av[lane] = __expf(v - m0);
  float lacc = m0;
  __syncthreads();
  for (int c = 0; c < 8; ++c) {
    float s = 0.f;
    if (lane < KK) {
      const float* mc = ws + OFF_CM2 + c*1600;
      for (int r = 0; r < KK; ++r) s += av[r]*mc[r*KK + lane];
    }
    float mx = s;
    #pragma unroll
    for (int m = 1; m <= 32; m <<= 1) mx = fmaxf(mx, __shfl_xor(mx, m));
    __syncthreads();
    if (lane < KK) av[lane] = s / mx;
    lacc += __logf(mx) + ws[OFF_LS2 + c];
    __syncthreads();
  }
  float tv = (lane < KK) ? av[lane]*__expf(ws[OFF_FIN + lane]) : 0.f;
  #pragma unroll
  for (int m = 1; m <= 32; m <<= 1) tv += __shfl_xor(tv, m);
  if (lane == 0) out[0] = lacc + __logf(tv);
}

extern "C" void kernel_launch(void* const* d_in, const int* in_sizes, int n_in,
                              void* d_out, int out_size, void* d_ws, size_t ws_size,
                              hipStream_t stream) {
  const float* E     = (const float*)d_in[0];
  const float* M     = (const float*)d_in[1];
  const float* MP    = (const float*)d_in[2];
  const float* T     = (const float*)d_in[3];
  const float* UA    = (const float*)d_in[4];
  const float* UB    = (const float*)d_in[5];
  const float* WlinA = (const float*)d_in[6];
  const float* WlinB = (const float*)d_in[7];
  const int*   words = (const int*)d_in[8];
  float* ws  = (float*)d_ws;       // needs WS_FLOATS*4 ~ 4.6 MB
  float* out = (float*)d_out;

  k1_prep<<<dim3(NN + 3), dim3(256), 0, stream>>>(E, M, MP, T, UA, UB, WlinB, words, ws);
  k2_rnn<<<dim3(32), dim3(64), 0, stream>>>(M, MP, ws);
  k3_pre<<<dim3(NN + 1), dim3(64), 0, stream>>>(UA, UB, ws);
  k4_coef<<<dim3(KK), dim3(640), 0, stream>>>(WlinA, ws);
  k5_expand<<<dim3(NN + 1), dim3(256), 0, stream>>>(ws);
  k6_chunk<<<dim3(64), dim3(256), 0, stream>>>(ws);
  k6b_chunk2<<<dim3(8), dim3(256), 0, stream>>>(ws);
  k7_final<<<dim3(1), dim3(64), 0, stream>>>(ws, out);
}